// Round 14
// baseline (149.011 us; speedup 1.0000x reference)
//
#include <hip/hip_runtime.h>

// FeatLUT: out[f] = quantize( mean_p( msb[idx_m(p)][f] + lsb[idx_l(p)][f] ) )
// idx = 16*(289*c0 + 17*c1 + c2)  -> only 17^3 = 4913 distinct rows used.
//
// Session mines (do not re-trip):
//  - 40960 same-cacheline global atomics serialized = 417us (orig session).
//  - __launch_bounds__ MIN-WAVES arg squeezes VGPR (52->28): 3x slower (R2).
//  - __threadfence + last-block finalize under concurrent streamers: 3-5x (R3/R4).
//  - COMPILER sinks loads: source hoist (R7) and sched_barrier pin (R8) both
//    null. Only asm volatile load issue is un-sinkable.
//  - 1-D merge grid (R9): 154 blocks = 0.6/CU -> 42.6us at 5.7% occupancy.
//
// R14 ledger (from R13, 148.6us): fills 2x41us (268MB ws poison, fixed) +
// kernels ~31 (feat_hist ~25 latency-bound at 3.9 TB/s) + gaps. Last lever:
// phase A via 24 inline-asm global_load_dwordx4 issued up front per thread
// (NH=512 x HT=512, 4 iters fully unrolled) -> 16 waves/CU x 384B = 6KB/CU
// in flight -> BW-bound. Staged vmcnt(18/12/6/0) + sched_barrier(0) fences
// (rule #18: consumers must not hoist above an asm waitcnt).

#define NBINS 4913            // 17^3
#define HPAD  4928            // padded hist row, dwords (154 * 32)
#define NPIX  (2048 * 2048)   // 4194304
#define G4    (NPIX / 4)      // 1048576 float4 groups per channel plane
#define NFEAT 20
#define NH    512             // hist rows / blocks
#define HT    512             // threads: 512x512 = 262144 -> 4 iters, no tail
#define BINGRP 154            // 154 * 32 = 4928 bins
#define ROWGRP 16             // merge row-groups -> 2464 merge blocks

// ws layout:
//   cm      @ 0      : 96 KiB  (4913 rows * 5 dwords)
//   cl      @ 98304  : 96 KiB
//   partial @ 196608 : 256 KiB region (2464*80 = 192.5 KiB used; legacy 80 KiB)
//   hists   @ 458752 : NH * 19712 B = 10.1 MB
#define PART_OFF 196608
#define HIST_OFF 458752

// ---------------------------------------------------------------------------
// Compact helper: row 16*j of the source table -> 5 packed dwords at cc[j*5].
// Handles both harness layouts (raw int8 bytes vs widened int32).
// ---------------------------------------------------------------------------
__device__ __forceinline__ void compact_range(const int* __restrict__ msb,
                                              const int* __restrict__ lsb,
                                              int* __restrict__ cm,
                                              int* __restrict__ cl,
                                              int t0, int stride) {
    int ok = 1;
    for (int i = 0; i < 64; ++i) {
        int v = msb[i];
        ok &= (v >= -32 && v < 32);
    }
    const bool is_int32 = (ok != 0);

    const int total = NBINS * 5;
    for (int t = t0; t < total; t += stride) {
        int j = t / 5;
        int k = t - j * 5;
        int wm, wl;
        if (is_int32) {
            const int* rm = msb + j * 320 + k * 4;
            const int* rl = lsb + j * 320 + k * 4;
            unsigned um = (unsigned)(rm[0] & 0xff) | ((unsigned)(rm[1] & 0xff) << 8) |
                          ((unsigned)(rm[2] & 0xff) << 16) | ((unsigned)(rm[3] & 0xff) << 24);
            unsigned ul = (unsigned)(rl[0] & 0xff) | ((unsigned)(rl[1] & 0xff) << 8) |
                          ((unsigned)(rl[2] & 0xff) << 16) | ((unsigned)(rl[3] & 0xff) << 24);
            wm = (int)um;
            wl = (int)ul;
        } else {
            wm = msb[j * 80 + k];
            wl = lsb[j * 80 + k];
        }
        cm[t] = wm;
        cl[t] = wl;
    }
}

// asm load: issue is pinned in program order (volatile), compiler cannot sink.
#define GLOAD(dst, addr)                                                    \
    asm volatile("global_load_dwordx4 %0, %1, off" : "=&v"(dst) : "v"(addr) : "memory")

#define IDX4(d, v0, v1, v2)                                      \
    int d##0 = (int)fmaf(v0.x, 289.0f, fmaf(v1.x, 17.0f, v2.x)); \
    int d##1 = (int)fmaf(v0.y, 289.0f, fmaf(v1.y, 17.0f, v2.y)); \
    int d##2 = (int)fmaf(v0.z, 289.0f, fmaf(v1.z, 17.0f, v2.z)); \
    int d##3 = (int)fmaf(v0.w, 289.0f, fmaf(v1.w, 17.0f, v2.w));

#define HIST8(m, s)                 \
    atomicAdd(&hist[m##0], 1);      \
    atomicAdd(&hist[m##1], 1);      \
    atomicAdd(&hist[m##2], 1);      \
    atomicAdd(&hist[m##3], 1);      \
    atomicAdd(&hist[s##0], 1 << 16);\
    atomicAdd(&hist[s##1], 1 << 16);\
    atomicAdd(&hist[s##2], 1 << 16);\
    atomicAdd(&hist[s##3], 1 << 16);

// ---------------------------------------------------------------------------
// Kernel 1: phase A (asm-pinned 24-deep load issue) + non-atomic hist write.
// NH x HT. Blocks 0-47 also run table compaction (consumed by merge_dot_k,
// ordered by the dispatch boundary).
// Packed hist: msb lo16 / lsb hi16 (per-block per-field count 8192 < 2^16).
// ---------------------------------------------------------------------------
__global__ __launch_bounds__(HT) void feat_hist(const float* __restrict__ xin,
                                                const float* __restrict__ xs,
                                                const int* __restrict__ msb,
                                                const int* __restrict__ lsb,
                                                int* __restrict__ cm,
                                                int* __restrict__ cl,
                                                unsigned* __restrict__ hists) {
    __shared__ int hist[NBINS];   // 19652 B; 2 blocks/CU (grid) x 8 waves
    for (int i = threadIdx.x; i < NBINS; i += HT) hist[i] = 0;

    if (blockIdx.x < 48)          // 48*512 = 24576 threads, 2 dwords each
        compact_range(msb, lsb, cm, cl, blockIdx.x * HT + threadIdx.x, 48 * HT);
    __syncthreads();

    const int tid = blockIdx.x * HT + threadIdx.x;   // 0..262143
    const unsigned long long nt16 = (unsigned long long)(NH * HT) * 16ull;
    unsigned long long pa = (unsigned long long)xin + (unsigned long long)tid * 16ull;
    unsigned long long pb = (unsigned long long)xs + (unsigned long long)tid * 16ull;
    const unsigned long long P = (unsigned long long)G4 * 16ull;  // plane bytes

    // issue all 24 loads (4 iters x 6 planes) before any consumer: 384B/wave
    // in flight x 16 waves/CU = 6KB/CU -> BW-bound phase A.
    float4 A00, A01, A02, B00, B01, B02;
    float4 A10, A11, A12, B10, B11, B12;
    float4 A20, A21, A22, B20, B21, B22;
    float4 A30, A31, A32, B30, B31, B32;
    GLOAD(A00, pa); GLOAD(A01, pa + P); GLOAD(A02, pa + 2 * P);
    GLOAD(B00, pb); GLOAD(B01, pb + P); GLOAD(B02, pb + 2 * P);
    pa += nt16; pb += nt16;
    GLOAD(A10, pa); GLOAD(A11, pa + P); GLOAD(A12, pa + 2 * P);
    GLOAD(B10, pb); GLOAD(B11, pb + P); GLOAD(B12, pb + 2 * P);
    pa += nt16; pb += nt16;
    GLOAD(A20, pa); GLOAD(A21, pa + P); GLOAD(A22, pa + 2 * P);
    GLOAD(B20, pb); GLOAD(B21, pb + P); GLOAD(B22, pb + 2 * P);
    pa += nt16; pb += nt16;
    GLOAD(A30, pa); GLOAD(A31, pa + P); GLOAD(A32, pa + 2 * P);
    GLOAD(B30, pb); GLOAD(B31, pb + P); GLOAD(B32, pb + 2 * P);

    // staged drains: consume group k while 6*(3-k) loads remain in flight.
    asm volatile("s_waitcnt vmcnt(18)" ::: "memory");
    __builtin_amdgcn_sched_barrier(0);
    { IDX4(m, A00, A01, A02) IDX4(s, B00, B01, B02) HIST8(m, s) }
    asm volatile("s_waitcnt vmcnt(12)" ::: "memory");
    __builtin_amdgcn_sched_barrier(0);
    { IDX4(m, A10, A11, A12) IDX4(s, B10, B11, B12) HIST8(m, s) }
    asm volatile("s_waitcnt vmcnt(6)" ::: "memory");
    __builtin_amdgcn_sched_barrier(0);
    { IDX4(m, A20, A21, A22) IDX4(s, B20, B21, B22) HIST8(m, s) }
    asm volatile("s_waitcnt vmcnt(0)" ::: "memory");
    __builtin_amdgcn_sched_barrier(0);
    { IDX4(m, A30, A31, A32) IDX4(s, B30, B31, B32) HIST8(m, s) }
    __syncthreads();

    // stream the packed hist out: coalesced stores, distinct rows, no atomics
    unsigned* row = hists + (size_t)blockIdx.x * HPAD;
    for (int i = threadIdx.x; i < HPAD; i += HT)
        row[i] = (i < NBINS) ? (unsigned)hist[i] : 0u;
}

// ---------------------------------------------------------------------------
// Kernel 2: 2-D merge. blockIdx.x: 32-bin group (154), blockIdx.y: row group
// (16, 32 rows each). 8 slices x 32 lanes sum 4 rows each; LDS combine;
// lanes 0..31 dot their bin once; 32-lane butterfly; one partial row/block.
// ---------------------------------------------------------------------------
__global__ __launch_bounds__(256) void merge_dot_k(const unsigned* __restrict__ hists,
                                                   const int* __restrict__ cm,
                                                   const int* __restrict__ cl,
                                                   int* __restrict__ partial) {
    __shared__ unsigned part[8][32];
    const int t = threadIdx.x;
    const int s = t >> 5;          // slice 0..7
    const int bo = t & 31;         // bin offset in group
    const int j = blockIdx.x * 32 + bo;   // < 4928 = HPAD, always in-row

    const int rpg = NH / ROWGRP;   // 32
    const int r0 = blockIdx.y * rpg;
    const int r1 = r0 + rpg;

    unsigned sum = 0;
    for (int b = r0 + s; b < r1; b += 8)
        sum += hists[(size_t)b * HPAD + j];
    part[s][bo] = sum;
    __syncthreads();

    if (t < 32) {
        unsigned h = 0;
#pragma unroll
        for (int ss = 0; ss < 8; ++ss) h += part[ss][bo];
        // whole-image per-bin counts ~853 avg per field: no 16-bit carry.
        int hm = (int)(h & 0xffffu);
        int hl = (int)(h >> 16);

        int acc[NFEAT];
#pragma unroll
        for (int f = 0; f < NFEAT; ++f) acc[f] = 0;
        if (j < NBINS && h != 0u) {
            const int* rm = cm + j * 5;
            const int* rl = cl + j * 5;
#pragma unroll
            for (int k = 0; k < 5; ++k) {
                int wm = rm[k], wl = rl[k];
                acc[4 * k + 0] += hm * ((wm << 24) >> 24) + hl * ((wl << 24) >> 24);
                acc[4 * k + 1] += hm * ((wm << 16) >> 24) + hl * ((wl << 16) >> 24);
                acc[4 * k + 2] += hm * ((wm << 8) >> 24) + hl * ((wl << 8) >> 24);
                acc[4 * k + 3] += hm * (wm >> 24) + hl * (wl >> 24);
            }
        }
#pragma unroll
        for (int f = 0; f < NFEAT; ++f) {
            int v = acc[f];
#pragma unroll
            for (int o = 16; o > 0; o >>= 1) v += __shfl_xor(v, o, 64);
            acc[f] = v;
        }
        if (t == 0) {
            const int row = blockIdx.y * BINGRP + blockIdx.x;
#pragma unroll
            for (int f = 0; f < NFEAT; ++f)
                partial[row * NFEAT + f] = acc[f];
        }
    }
}

// ---------------------------------------------------------------------------
// Legacy fallback (small ws): R5's proven 3-dispatch path.
// ---------------------------------------------------------------------------
__global__ __launch_bounds__(256) void compact_k(const int* __restrict__ msb,
                                                 const int* __restrict__ lsb,
                                                 int* __restrict__ cm,
                                                 int* __restrict__ cl) {
    compact_range(msb, lsb, cm, cl, blockIdx.x * 256 + threadIdx.x, gridDim.x * 256);
}

__global__ __launch_bounds__(256) void feat_dot(const float* __restrict__ xin,
                                                const float* __restrict__ xs,
                                                const int* __restrict__ cm,
                                                const int* __restrict__ cl,
                                                int* __restrict__ partial) {
    __shared__ int hist[NBINS];
    __shared__ int wsum[4][NFEAT];
    for (int i = threadIdx.x; i < NBINS; i += 256) hist[i] = 0;
    __syncthreads();

    const float4* a = (const float4*)xin;
    const float4* b = (const float4*)xs;
    const int nt = gridDim.x * 256;
    for (int g = blockIdx.x * 256 + threadIdx.x; g < G4; g += nt) {
        float4 a0 = a[g], a1 = a[g + G4], a2 = a[g + 2 * G4];
        float4 b0 = b[g], b1 = b[g + G4], b2 = b[g + 2 * G4];
        IDX4(m, a0, a1, a2)
        IDX4(s, b0, b1, b2)
        HIST8(m, s)
    }
    __syncthreads();

    int acc[NFEAT];
#pragma unroll
    for (int f = 0; f < NFEAT; ++f) acc[f] = 0;
    for (int j = threadIdx.x; j < NBINS; j += 256) {
        int h = hist[j];
        int hm = h & 0xffff;
        int hl = (int)((unsigned)h >> 16);
        if (hm) {
            const int* r = cm + j * 5;
#pragma unroll
            for (int k = 0; k < 5; ++k) {
                int w = r[k];
                acc[4 * k + 0] += hm * ((w << 24) >> 24);
                acc[4 * k + 1] += hm * ((w << 16) >> 24);
                acc[4 * k + 2] += hm * ((w << 8) >> 24);
                acc[4 * k + 3] += hm * (w >> 24);
            }
        }
        if (hl) {
            const int* r = cl + j * 5;
#pragma unroll
            for (int k = 0; k < 5; ++k) {
                int w = r[k];
                acc[4 * k + 0] += hl * ((w << 24) >> 24);
                acc[4 * k + 1] += hl * ((w << 16) >> 24);
                acc[4 * k + 2] += hl * ((w << 8) >> 24);
                acc[4 * k + 3] += hl * (w >> 24);
            }
        }
    }

    const int lane = threadIdx.x & 63;
    const int wv = threadIdx.x >> 6;
#pragma unroll
    for (int f = 0; f < NFEAT; ++f) {
        int v = acc[f];
#pragma unroll
        for (int o = 32; o > 0; o >>= 1) v += __shfl_xor(v, o, 64);
        if (lane == 0) wsum[wv][f] = v;
    }
    __syncthreads();
    if (threadIdx.x < NFEAT) {
        int f = threadIdx.x;
        partial[blockIdx.x * NFEAT + f] = wsum[0][f] + wsum[1][f] + wsum[2][f] + wsum[3][f];
    }
}

// ---------------------------------------------------------------------------
// Kernel 3: finalize. Block f sums partial[b][f] over nb rows; exact quantize.
// ---------------------------------------------------------------------------
__global__ __launch_bounds__(64) void finalize_k(const int* __restrict__ partial,
                                                 float* __restrict__ out, int nb) {
    const int f = blockIdx.x;
    const int lane = threadIdx.x;
    int s = 0;
    for (int b = lane; b < nb; b += 64) s += partial[b * NFEAT + f];
#pragma unroll
    for (int o = 32; o > 0; o >>= 1) s += __shfl_xor(s, o, 64);
    if (lane == 0) {
        double m4 = (double)s * (1.0 / 1048576.0);   // mean*4 = S / 2^20 exact
        double r = rint(m4);                          // RNE == jnp.round
        float v = (float)(r * 0.25);
        v = fminf(fmaxf(v, -32.0f), 31.75f);
        out[f] = v;
    }
}

extern "C" void kernel_launch(void* const* d_in, const int* in_sizes, int n_in,
                              void* d_out, int out_size, void* d_ws, size_t ws_size,
                              hipStream_t stream) {
    const float* xin = (const float*)d_in[0];
    const float* xs = (const float*)d_in[1];
    const int* msb = (const int*)d_in[2];
    const int* lsb = (const int*)d_in[3];
    float* out = (float*)d_out;

    int* cm = (int*)d_ws;
    int* cl = (int*)((char*)d_ws + 98304);
    int* partial = (int*)((char*)d_ws + PART_OFF);
    unsigned* hists = (unsigned*)((char*)d_ws + HIST_OFF);

    const size_t need = (size_t)HIST_OFF + (size_t)NH * HPAD * 4;   // ~10.6 MB
    if (ws_size >= need) {
        feat_hist<<<NH, HT, 0, stream>>>(xin, xs, msb, lsb, cm, cl, hists);
        merge_dot_k<<<dim3(BINGRP, ROWGRP), 256, 0, stream>>>(hists, cm, cl, partial);
        finalize_k<<<NFEAT, 64, 0, stream>>>(partial, out, BINGRP * ROWGRP);
    } else {
        compact_k<<<96, 256, 0, stream>>>(msb, lsb, cm, cl);
        feat_dot<<<1024, 256, 0, stream>>>(xin, xs, cm, cl, partial);
        finalize_k<<<NFEAT, 64, 0, stream>>>(partial, out, 1024);
    }
}